// Round 1
// baseline (951.997 us; speedup 1.0000x reference)
//
#include <hip/hip_runtime.h>
#include <hip/hip_bf16.h>

// Block-diagonal equivariant linear on MI355X.
// out[n, off + w*d + i] = ALPHA * sum_u x[n, off + u*d + i] * W[u, w]
// Strategy: fp32 -> bf16, MFMA 16x16x32, memory-bound (~922 MB traffic).

typedef __attribute__((ext_vector_type(8))) short short8;
typedef __attribute__((ext_vector_type(4))) float floatx4;

#define ALPHA 0.08838834764831845f
#define FEAT 1152

__device__ inline unsigned short bf16_rne(float f) {
    unsigned int u = __float_as_uint(f);
    unsigned int r = u + 0x7fffu + ((u >> 16) & 1u);
    return (unsigned short)(r >> 16);
}

template <int D, int OFF>
__launch_bounds__(256, 3)
__global__ void eq_linear_kernel(const float* __restrict__ x,
                                 const float* __restrict__ w,
                                 float* __restrict__ out, int n) {
    constexpr int C = 128 * D;                       // columns in this block
    constexpr int PITCH = (D == 1) ? 136 : (C + 2);  // LDS row pitch (elems), breaks bank aliasing
    constexpr int R = 32;                            // rows per workgroup
    __shared__ unsigned short xs[R * PITCH];

    const int tid = threadIdx.x;
    const int lane = tid & 63;
    const int wave = tid >> 6;
    const int rowbase = blockIdx.x * R;

    // ---- stage x tile: coalesced float4 global loads -> bf16 -> LDS ----
    constexpr int C4 = C / 4;
    constexpr int ITERS = (R * C4) / 256;  // exact for d=1,3,5
    for (int it = 0; it < ITERS; ++it) {
        int idx = tid + it * 256;
        int r = idx / C4;          // constexpr divisor -> magic mul
        int c4 = idx - r * C4;
        float4 v = make_float4(0.f, 0.f, 0.f, 0.f);
        if (rowbase + r < n) {
            const float4* gp = reinterpret_cast<const float4*>(
                x + (size_t)(rowbase + r) * FEAT + OFF) + c4;
            v = *gp;
        }
        unsigned int p0 = (unsigned int)bf16_rne(v.x) | ((unsigned int)bf16_rne(v.y) << 16);
        unsigned int p1 = (unsigned int)bf16_rne(v.z) | ((unsigned int)bf16_rne(v.w) << 16);
        unsigned int* lp = reinterpret_cast<unsigned int*>(&xs[r * PITCH + c4 * 4]);
        lp[0] = p0;
        lp[1] = p1;
    }

    // ---- B fragments: W fp32 from global (L2-hot) -> bf16 regs, once per WG ----
    const int mtile = wave & 1;    // which 16-row M-tile
    const int nthalf = wave >> 1;  // which half of the 8 n-tiles
    const int l16 = lane & 15;
    const int quad = lane >> 4;

    short8 bfrag[4][4];  // [ntl][kstep]
    for (int ntl = 0; ntl < 4; ++ntl) {
        int wcol = (nthalf * 4 + ntl) * 16 + l16;
        for (int k = 0; k < 4; ++k) {
            int u0 = k * 32 + quad * 8;
            short8 f;
#pragma unroll
            for (int j = 0; j < 8; ++j) {
                f[j] = (short)bf16_rne(w[(u0 + j) * 128 + wcol]);
            }
            bfrag[ntl][k] = f;
        }
    }

    __syncthreads();

    // ---- compute + store ----
    const int arow = mtile * 16 + l16;                  // local row for A frags
    const int orow0 = rowbase + mtile * 16 + quad * 4;  // global out row base (C/D layout)

    for (int i = 0; i < D; ++i) {
        floatx4 acc[4] = {floatx4{0,0,0,0}, floatx4{0,0,0,0},
                          floatx4{0,0,0,0}, floatx4{0,0,0,0}};
#pragma unroll
        for (int k = 0; k < 4; ++k) {
            short8 a;
            if (D == 1) {
                a = *reinterpret_cast<const short8*>(&xs[arow * PITCH + k * 32 + quad * 8]);
            } else {
                int base = arow * PITCH + (k * 32 + quad * 8) * D + i;
#pragma unroll
                for (int j = 0; j < 8; ++j) a[j] = (short)xs[base + j * D];
            }
#pragma unroll
            for (int ntl = 0; ntl < 4; ++ntl) {
                acc[ntl] = __builtin_amdgcn_mfma_f32_16x16x32_bf16(
                    a, bfrag[ntl][k], acc[ntl], 0, 0, 0);
            }
        }
#pragma unroll
        for (int ntl = 0; ntl < 4; ++ntl) {
            int wcol = (nthalf * 4 + ntl) * 16 + l16;
            int col = OFF + wcol * D + i;
#pragma unroll
            for (int r = 0; r < 4; ++r) {
                if (orow0 + r < n) {
                    out[(size_t)(orow0 + r) * FEAT + col] = acc[ntl][r] * ALPHA;
                }
            }
        }
    }
}

extern "C" void kernel_launch(void* const* d_in, const int* in_sizes, int n_in,
                              void* d_out, int out_size, void* d_ws, size_t ws_size,
                              hipStream_t stream) {
    const float* x  = (const float*)d_in[0];
    const float* w0 = (const float*)d_in[1];
    const float* w1 = (const float*)d_in[2];
    const float* w2 = (const float*)d_in[3];
    float* out = (float*)d_out;

    int n = in_sizes[0] / FEAT;
    int grid = (n + 31) / 32;
    dim3 blk(256);

    eq_linear_kernel<1, 0>  <<<grid, blk, 0, stream>>>(x, w0, out, n);
    eq_linear_kernel<3, 128><<<grid, blk, 0, stream>>>(x, w1, out, n);
    eq_linear_kernel<5, 512><<<grid, blk, 0, stream>>>(x, w2, out, n);
}